// Round 1
// baseline (205.746 us; speedup 1.0000x reference)
//
#include <hip/hip_runtime.h>

typedef unsigned short u16;
typedef unsigned int   u32;

#define NB     20000   // batch of target nodes
#define SNB    25      // sampled neighbors (padded)
#define FEAT   256
#define K2     512     // 2*FEAT (concat dim)
#define OUTF   256

// Fused geometry: block = 32 nodes, 4 waves, 8 nodes/wave.
// LDS: As (combined rows, bf16) 32 x 520 x 2B = 33,280 B
//      Bs (W k-chunk,     bf16) 256 x 40 x 2B = 20,480 B   -> 53,760 B total
// => 3 blocks/CU co-resident (gather phase of one block overlaps MFMA of another).
#define BM     32
#define NPW    8            // nodes per wave
#define LDA    520          // A row stride, elems (512 + 8 pad)
#define BK     32
#define LDB    40           // B row stride, elems (32 + 8 pad)
#define NCHUNK (K2 / BK)    // 16

typedef __attribute__((ext_vector_type(8))) short short8;
typedef __attribute__((ext_vector_type(4))) float f32x4;

__device__ __forceinline__ u32 f2bf(float f) {
  union { u32 i; float f; } x; x.f = f;
  return (x.i + 0x7fffu + ((x.i >> 16) & 1u)) >> 16;  // RNE
}
__device__ __forceinline__ u32 pack2(float a, float b) {
  return f2bf(a) | (f2bf(b) << 16);
}

// ---------------------------------------------------------------------------
// w1 f32 -> bf16 (131072 elements). Kept: halves the W-stream bytes in the
// fused kernel's k-loop for ~3 us.
// ---------------------------------------------------------------------------
__global__ __launch_bounds__(256) void convw_kernel(
    const float* __restrict__ w_raw, u16* __restrict__ w_bf) {
  const int i = blockIdx.x * 256 + threadIdx.x;
  w_bf[i] = (u16)f2bf(w_raw[i]);
}

// ---------------------------------------------------------------------------
// Fused aggregate + GEMM:
//   phase 1: wave w aggregates nodes [wave*8, wave*8+8): self row (bf16-RNE)
//            and ragged mean of neighbors, written straight to LDS As.
//            (identical gather inner loop to the proven agg_kernel: 4 gathers
//             in flight, float4 per lane, __shfl-broadcast indices.)
//   phase 2: out[32,256] = relu(As[32,512] @ W[256,512]^T). A is LDS-resident
//            for the whole K; only W streams through Bs in 16 chunks of K=32.
//            Wave w owns the 64-wide N-slice [wave*64, wave*64+64).
// 'combined' never touches HBM (-61 MB round trip vs. split kernels).
// ---------------------------------------------------------------------------
__global__ __launch_bounds__(256) void fused_kernel(
    const float* __restrict__ feats, const int* __restrict__ nodes,
    const int* __restrict__ neighs, const int* __restrict__ lens,
    const u16* __restrict__ W, float* __restrict__ C) {
  __shared__ u16 As[BM * LDA];
  __shared__ u16 Bs[OUTF * LDB];

  const int tid   = threadIdx.x;
  const int wave  = tid >> 6;
  const int lane  = tid & 63;
  const int mbase = blockIdx.x * BM;

  // ---- prefetch B chunk 0 (independent of phase 1; overlaps the gathers) ---
  {
    const uint4* src = (const uint4*)(W + (size_t)tid * K2);  // row=tid, k=0..31
    uint4* dst = (uint4*)&Bs[tid * LDB];
#pragma unroll
    for (int c = 0; c < 4; ++c) dst[c] = src[c];
  }

  // ---- phase 1: aggregate 8 nodes per wave into As ----
  for (int p = 0; p < NPW; ++p) {
    const int m = wave * NPW + p;         // local row 0..31
    const int b = mbase + m;              // global node (exact: 625*32 = 20000)
    const int self = nodes[b];
    const int len  = lens[b];             // >= 1 guaranteed
    int myidx = (lane < SNB) ? neighs[b * SNB + lane] : 0;

    const float4 sv = ((const float4*)(feats + (size_t)self * FEAT))[lane];

    float4 a0 = {0.f, 0.f, 0.f, 0.f}, a1 = a0, a2 = a0, a3 = a0;
    int s = 0;
    for (; s + 4 <= len; s += 4) {        // len is wave-uniform -> cheap branch
      const int i0 = __shfl(myidx, s);
      const int i1 = __shfl(myidx, s + 1);
      const int i2 = __shfl(myidx, s + 2);
      const int i3 = __shfl(myidx, s + 3);
      const float4 v0 = ((const float4*)(feats + (size_t)i0 * FEAT))[lane];
      const float4 v1 = ((const float4*)(feats + (size_t)i1 * FEAT))[lane];
      const float4 v2 = ((const float4*)(feats + (size_t)i2 * FEAT))[lane];
      const float4 v3 = ((const float4*)(feats + (size_t)i3 * FEAT))[lane];
      a0.x += v0.x; a0.y += v0.y; a0.z += v0.z; a0.w += v0.w;
      a1.x += v1.x; a1.y += v1.y; a1.z += v1.z; a1.w += v1.w;
      a2.x += v2.x; a2.y += v2.y; a2.z += v2.z; a2.w += v2.w;
      a3.x += v3.x; a3.y += v3.y; a3.z += v3.z; a3.w += v3.w;
    }
    for (; s < len; ++s) {
      const int i0 = __shfl(myidx, s);
      const float4 v0 = ((const float4*)(feats + (size_t)i0 * FEAT))[lane];
      a0.x += v0.x; a0.y += v0.y; a0.z += v0.z; a0.w += v0.w;
    }
    const float inv = 1.f / (float)len;
    const float m0 = (a0.x + a1.x + a2.x + a3.x) * inv;
    const float m1 = (a0.y + a1.y + a2.y + a3.y) * inv;
    const float m2 = (a0.z + a1.z + a2.z + a3.z) * inv;
    const float m3 = (a0.w + a1.w + a2.w + a3.w) * inv;

    // combined[m, 0:256] = self, [256:512] = mean; bf16 RNE (same as before)
    uint2* arow = (uint2*)&As[m * LDA];   // byte base m*1040, 8B-aligned
    uint2 pe; pe.x = pack2(sv.x, sv.y); pe.y = pack2(sv.z, sv.w);
    arow[lane] = pe;                      // elems m*520 + lane*4
    uint2 pm; pm.x = pack2(m0, m1); pm.y = pack2(m2, m3);
    arow[64 + lane] = pm;                 // elems m*520 + 256 + lane*4
  }
  __syncthreads();                        // As complete, Bs chunk 0 complete

  // ---- phase 2: GEMM. wave -> N-slice [wave*64, wave*64+64) ----
  const int wc  = wave * 64;
  const int r16 = lane & 15;
  const int kq  = (lane >> 4) * 8;        // k-offset of this lane's quad

  f32x4 acc[2][4] = {};

  for (int kc = 0; ; ) {
    const int k0 = kc * BK;
    short8 af[2], bf[4];
#pragma unroll
    for (int i = 0; i < 2; ++i)
      af[i] = *(const short8*)&As[(i * 16 + r16) * LDA + k0 + kq];
#pragma unroll
    for (int j = 0; j < 4; ++j)
      bf[j] = *(const short8*)&Bs[(wc + j * 16 + r16) * LDB + kq];

#pragma unroll
    for (int i = 0; i < 2; ++i)
#pragma unroll
      for (int j = 0; j < 4; ++j)
        acc[i][j] = __builtin_amdgcn_mfma_f32_16x16x32_bf16(af[i], bf[j],
                                                            acc[i][j], 0, 0, 0);
    if (++kc == NCHUNK) break;
    __syncthreads();   // all waves done reading old Bs (frags are in regs)
    {
      const uint4* src = (const uint4*)(W + (size_t)tid * K2 + kc * BK);
      uint4* dst = (uint4*)&Bs[tid * LDB];
#pragma unroll
      for (int c = 0; c < 4; ++c) dst[c] = src[c];
    }
    __syncthreads();   // next Bs chunk ready
  }

  // ---- epilogue: C/D layout col = lane&15, row = (lane>>4)*4 + reg [m89] ----
#pragma unroll
  for (int i = 0; i < 2; ++i)
#pragma unroll
    for (int r = 0; r < 4; ++r) {
      const int row = mbase + i * 16 + (lane >> 4) * 4 + r;  // always < 20000
#pragma unroll
      for (int j = 0; j < 4; ++j) {
        const int col = wc + j * 16 + (lane & 15);
        const float v = acc[i][j][r];
        C[(size_t)row * OUTF + col] = v > 0.f ? v : 0.f;
      }
    }
}

// ---------------------------------------------------------------------------
extern "C" void kernel_launch(void* const* d_in, const int* in_sizes, int n_in,
                              void* d_out, int out_size, void* d_ws, size_t ws_size,
                              hipStream_t stream) {
  const float* feats = (const float*)d_in[0];  // [100000, 256] f32
  const int* nodes   = (const int*)d_in[1];    // [20000]
  const int* neighs  = (const int*)d_in[2];    // [20000, 25]
  const int* lens    = (const int*)d_in[3];    // [20000]
  // d_in[4] = w0 — dead: layer-0 output is discarded by the reference loop.
  const float* w1    = (const float*)d_in[5];  // [256, 512] f32
  float* out = (float*)d_out;                  // [20000, 256] f32

  u16* w1bf = (u16*)d_ws;                      // [256, 512] bf16 (262,144 B)

  convw_kernel<<<512, 256, 0, stream>>>(w1, w1bf);
  fused_kernel<<<NB / BM, 256, 0, stream>>>(feats, nodes, neighs, lens, w1bf, out);
}